// Round 9
// baseline (509.173 us; speedup 1.0000x reference)
//
#include <hip/hip_runtime.h>

#define BATCH 2
#define SEQL 2048
#define DM 1024
#define DSTATE 128
#define HD 64
#define CHUNK 256
#define DI 2048
#define NHEADS 32
#define CONVD 2304
#define DPROJ 4384
#define DFF 4096
#define NC 8
#define ROWS (BATCH*SEQL)

typedef unsigned short ushort_t;
typedef short bf16x8 __attribute__((ext_vector_type(8)));
typedef float f32x4 __attribute__((ext_vector_type(4)));

__device__ __forceinline__ float softplus_f(float v){
    return (v > 20.f) ? v : log1pf(expf(v));
}
__device__ __forceinline__ float silu_f(float v){
    return v / (1.f + expf(-v));
}
__device__ __forceinline__ ushort_t f2b(float v){
    union { float f; unsigned int u; } x; x.f = v;
    unsigned int r = x.u + 0x7fffu + ((x.u >> 16) & 1u);
    return (ushort_t)(r >> 16);
}
__device__ __forceinline__ float b2f(ushort_t v){
    union { unsigned int u; float f; } x; x.u = ((unsigned int)v) << 16;
    return x.f;
}

// ================================================================ MFMA GEMM
// C[M,N] = A[M,K](bf16) @ Bt[N,K](bf16)^T + bias. BM=128, BN=TN, BK=64.
// XOR-swizzled LDS. NS split-K. DTX: fp32 sidecar for last NHEADS cols.
template<int ACT, int OUT_BF16, int TN, int NS, int DTX>
__global__ __launch_bounds__(256) void mfma_gemm_k(
    const ushort_t* __restrict__ A, const ushort_t* __restrict__ Bt,
    const float* __restrict__ bias, float* __restrict__ Cf,
    ushort_t* __restrict__ Cb, float* __restrict__ dtaux,
    int M, int N, int K, int ldc)
{
    constexpr int NT = (TN == 128) ? 4 : 2;
    constexpr int BROWS = TN / 4;
    __shared__ ushort_t As[128*64];
    __shared__ ushort_t Bs[TN*64];
    int tid = threadIdx.x;
    int lane = tid & 63, wave = tid >> 6;
    int m0 = blockIdx.y * 128, n0 = blockIdx.x * TN;
    int Ks = K / NS;
    int kb = (NS > 1) ? blockIdx.z * Ks : 0;
    int wave_m = (TN==128) ? (wave >> 1)*64 : (wave & 1)*64;
    int wave_n = (TN==128) ? (wave & 1)*64 : (wave >> 1)*32;
    int lrow = lane >> 3;
    int lcol = ((lane & 7) ^ lrow) * 8;
    const ushort_t* Abase = A  + (size_t)(m0 + wave*32    + lrow)*K + lcol + kb;
    const ushort_t* Bbase = Bt + (size_t)(n0 + wave*BROWS + lrow)*K + lcol + kb;
    ushort_t* AsW = &As[(wave*32)*64];
    ushort_t* BsW = &Bs[(wave*BROWS)*64];
    f32x4 acc[4][NT];
    #pragma unroll
    for (int i=0;i<4;i++)
        #pragma unroll
        for (int j=0;j<NT;j++) acc[i][j] = (f32x4){0.f,0.f,0.f,0.f};
    int lm = lane & 15;
    int quad = lane >> 4;
    for (int k0 = 0; k0 < Ks; k0 += 64){
        #pragma unroll
        for (int j = 0; j < 4; j++)
            __builtin_amdgcn_global_load_lds(
                (const __attribute__((address_space(1))) void*)(Abase + (size_t)(j*8)*K + k0),
                (__attribute__((address_space(3))) void*)(AsW + j*8*64), 16, 0, 0);
        #pragma unroll
        for (int j = 0; j < BROWS/8; j++)
            __builtin_amdgcn_global_load_lds(
                (const __attribute__((address_space(1))) void*)(Bbase + (size_t)(j*8)*K + k0),
                (__attribute__((address_space(3))) void*)(BsW + j*8*64), 16, 0, 0);
        __syncthreads();
        #pragma unroll
        for (int kk = 0; kk < 64; kk += 32){
            int cb = kk >> 3;
            bf16x8 af[4], bfr[NT];
            #pragma unroll
            for (int mt=0; mt<4; mt++)
                af[mt] = *(const bf16x8*)&As[(wave_m + mt*16 + lm)*64 + (((cb + quad) ^ (lm & 7))*8)];
            #pragma unroll
            for (int nt=0; nt<NT; nt++)
                bfr[nt] = *(const bf16x8*)&Bs[(wave_n + nt*16 + lm)*64 + (((cb + quad) ^ (lm & 7))*8)];
            #pragma unroll
            for (int mt=0; mt<4; mt++)
                #pragma unroll
                for (int nt=0; nt<NT; nt++)
                    acc[mt][nt] = __builtin_amdgcn_mfma_f32_16x16x32_bf16(af[mt], bfr[nt], acc[mt][nt], 0, 0, 0);
        }
        __syncthreads();
    }
    float* Cfo = Cf + (size_t)((NS > 1) ? blockIdx.z : 0) * (size_t)M * ldc;
    int addb = (NS == 1) || (blockIdx.z == 0);
    int crow0 = m0 + wave_m + quad * 4;
    int ccol0 = n0 + wave_n + lm;
    #pragma unroll
    for (int mt=0; mt<4; mt++){
        #pragma unroll
        for (int nt=0; nt<NT; nt++){
            int col = ccol0 + nt*16;
            if (col < N){
                float bv = addb ? bias[col] : 0.f;
                #pragma unroll
                for (int r=0; r<4; r++){
                    int row = crow0 + mt*16 + r;
                    float v = acc[mt][nt][r] + bv;
                    if (ACT == 1){
                        float t = fminf(fmaxf(v + 3.f, 0.f), 6.f);
                        v = v * t * (1.f/6.f);
                    }
                    if (OUT_BF16){
                        Cb[(size_t)row*ldc + col] = f2b(v);
                        if (DTX && col >= N - NHEADS)
                            dtaux[(size_t)row*NHEADS + (col - (N - NHEADS))] = v;
                    } else {
                        Cfo[(size_t)row*ldc + col] = v;
                    }
                }
            }
        }
    }
}

// ------- merged: f2b(x) vectorized [blocks 0..2047] + W_in transpose [rest]
__global__ __launch_bounds__(256) void prep_in_k(const float* __restrict__ x,
                                                 ushort_t* __restrict__ x_bf,
                                                 const float* __restrict__ W_in,
                                                 ushort_t* __restrict__ WinT){
    __shared__ ushort_t tile[32][33];
    int bid = blockIdx.x;
    if (bid < 2048){
        int idx = (bid*256 + threadIdx.x)*8;
        float4 a = *(const float4*)&x[idx];
        float4 b = *(const float4*)&x[idx+4];
        bf16x8 o;
        o[0]=(short)f2b(a.x); o[1]=(short)f2b(a.y); o[2]=(short)f2b(a.z); o[3]=(short)f2b(a.w);
        o[4]=(short)f2b(b.x); o[5]=(short)f2b(b.y); o[6]=(short)f2b(b.z); o[7]=(short)f2b(b.w);
        *(bf16x8*)&x_bf[idx] = o;
        return;
    }
    int id2 = bid - 2048;                  // 4480 transpose blocks (140 x 32)
    int n0 = (id2 % 140)*32, k0 = (id2 / 140)*32;
    int tx = threadIdx.x & 31, ty = threadIdx.x >> 5;
    #pragma unroll
    for (int i = 0; i < 4; i++){
        int k = k0 + ty + i*8;
        int n = n0 + tx;
        float v = (n < DPROJ) ? W_in[(size_t)k*DPROJ + n] : 0.f;
        tile[ty + i*8][tx] = f2b(v);
    }
    __syncthreads();
    #pragma unroll
    for (int i = 0; i < 4; i++)
        WinT[(size_t)(n0 + ty + i*8)*DM + k0 + tx] = tile[tx][ty + i*8];
}

// ---------------- merged: W_out / fc1 / fc2 transposes in one launch
__global__ __launch_bounds__(256) void transpose3_k(const float* __restrict__ Wout,
                                                    const float* __restrict__ fc1w,
                                                    const float* __restrict__ fc2w,
                                                    ushort_t* __restrict__ WoutT,
                                                    ushort_t* __restrict__ fc1T,
                                                    ushort_t* __restrict__ fc2T){
    __shared__ ushort_t tile[32][33];
    int bid = blockIdx.x;
    const float* W; ushort_t* Wt; int K, N, gx, id;
    if (bid < 2048){        W = Wout; Wt = WoutT; K = DI;  N = DM;  gx = 32;  id = bid; }
    else if (bid < 6144){   W = fc1w; Wt = fc1T;  K = DM;  N = DFF; gx = 128; id = bid - 2048; }
    else {                  W = fc2w; Wt = fc2T;  K = DFF; N = DM;  gx = 32;  id = bid - 6144; }
    int n0 = (id % gx)*32, k0 = (id / gx)*32;
    int tx = threadIdx.x & 31, ty = threadIdx.x >> 5;
    #pragma unroll
    for (int i = 0; i < 4; i++){
        int k = k0 + ty + i*8;
        int n = n0 + tx;
        tile[ty + i*8][tx] = f2b(W[(size_t)k*N + n]);
    }
    __syncthreads();
    #pragma unroll
    for (int i = 0; i < 4; i++)
        Wt[(size_t)(n0 + ty + i*8)*K + k0 + tx] = tile[tx][ty + i*8];
}

// -- merged: [0, 4608) conv+SiLU vectorized (8 c/thread); [4608, +512) dt-scan
#define CONVBLKS (ROWS*CONVD/(256*8))
__global__ __launch_bounds__(256) void conv_dt_k(const ushort_t* __restrict__ zx,
                                                 const float* __restrict__ conv_w,
                                                 const float* __restrict__ conv_b,
                                                 ushort_t* __restrict__ convb,
                                                 const float* __restrict__ dtaux,
                                                 const float* __restrict__ time_diff,
                                                 const float* __restrict__ A_log,
                                                 const float* __restrict__ dt_bias,
                                                 const float* __restrict__ time_decay,
                                                 float* __restrict__ dtH,
                                                 float* __restrict__ Acum){
    __shared__ float s[CHUNK];
    int bid = blockIdx.x;
    if (bid < CONVBLKS){
        int idx8 = bid*256 + threadIdx.x;
        int c0 = (idx8*8) % CONVD;
        int row = (idx8*8) / CONVD;
        int t = row & (SEQL-1);
        float4 cb0 = *(const float4*)&conv_b[c0];
        float4 cb1 = *(const float4*)&conv_b[c0+4];
        float acc[8] = {cb0.x, cb0.y, cb0.z, cb0.w, cb1.x, cb1.y, cb1.z, cb1.w};
        #pragma unroll
        for (int k = 0; k < 4; k++){
            if (t + k - 3 >= 0){
                bf16x8 z8 = *(const bf16x8*)&zx[((size_t)(row + k - 3))*DPROJ + DI + c0];
                #pragma unroll
                for (int j = 0; j < 8; j++)
                    acc[j] += b2f((ushort_t)z8[j]) * conv_w[(c0+j)*4 + k];
            }
        }
        bf16x8 o;
        #pragma unroll
        for (int j = 0; j < 8; j++) o[j] = (short)f2b(silu_f(acc[j]));
        *(bf16x8*)&convb[(size_t)idx8*8] = o;
        return;
    }
    int id2 = bid - CONVBLKS;                  // 512 dt blocks
    int c = id2 % NC;
    int h = (id2 / NC) % NHEADS;
    int b = id2 / (NC*NHEADS);
    int l = threadIdx.x;
    int t = c*CHUNK + l;
    float dtr = dtaux[((size_t)(b*SEQL + t))*NHEADS + h];
    float dtv = softplus_f(dtr + dt_bias[h]);
    float A = -expf(A_log[h]);
    float dA = dtv*A - softplus_f(time_decay[h]) * time_diff[b*SEQL + t];
    dtH[((size_t)(b*NHEADS + h))*SEQL + t] = dtv;        // [h][row] layout
    s[l] = dA;
    __syncthreads();
    for (int off = 1; off < CHUNK; off <<= 1){
        float v = (l >= off) ? s[l-off] : 0.f;
        __syncthreads();
        s[l] += v;
        __syncthreads();
    }
    Acum[((size_t)(b*NHEADS + h))*SEQL + t] = s[l];
}

// -------------------- MFMA G[b,c,l,s] = C_l . B_s (64x64x128), bf16 in/out
__global__ __launch_bounds__(256) void g_mfma_k(const ushort_t* __restrict__ convb,
                                                ushort_t* __restrict__ G){
    __shared__ ushort_t As[64*136];
    __shared__ ushort_t Bs[64*136];
    int bc = blockIdx.z;
    int l0 = blockIdx.y*64, s0 = blockIdx.x*64;
    int tid = threadIdx.x;
    int lane = tid & 63, wave = tid >> 6;
    int lm = lane & 15, quad = lane >> 4;
    const ushort_t* base = convb + (size_t)bc*CHUNK*CONVD;
    #pragma unroll
    for (int i = 0; i < 4; i++){
        int e = tid + i*256;
        int r = e >> 4, k = (e & 15)*8;
        *(bf16x8*)&As[r*136 + k] = *(const bf16x8*)&base[(size_t)(l0+r)*CONVD + DI + DSTATE + k];
        *(bf16x8*)&Bs[r*136 + k] = *(const bf16x8*)&base[(size_t)(s0+r)*CONVD + DI + k];
    }
    __syncthreads();
    f32x4 acc[4];
    #pragma unroll
    for (int j=0;j<4;j++) acc[j] = (f32x4){0.f,0.f,0.f,0.f};
    #pragma unroll
    for (int kk = 0; kk < 4; kk++){
        bf16x8 af = *(const bf16x8*)&As[(wave*16+lm)*136 + kk*32 + quad*8];
        #pragma unroll
        for (int nt = 0; nt < 4; nt++){
            bf16x8 bfr = *(const bf16x8*)&Bs[(nt*16+lm)*136 + kk*32 + quad*8];
            acc[nt] = __builtin_amdgcn_mfma_f32_16x16x32_bf16(af, bfr, acc[nt], 0, 0, 0);
        }
    }
    ushort_t* g = G + (size_t)bc*CHUNK*CHUNK;
    #pragma unroll
    for (int nt = 0; nt < 4; nt++)
        #pragma unroll
        for (int r = 0; r < 4; r++)
            g[(size_t)(l0 + wave*16 + quad*4 + r)*CHUNK + s0 + nt*16 + lm] = f2b(acc[nt][r]);
}

// ---- MFMA states[b,c,h,p,n] = sum_l B[l,n]*exp(AcL-Ac[l])*dt[l]*xs[l,p]
#define RSX 264
#define RSB 72
__global__ __launch_bounds__(256) void states_mfma_k(const ushort_t* __restrict__ convb,
                                                     const float* __restrict__ dtH,
                                                     const float* __restrict__ Acum,
                                                     float* __restrict__ states){
    __shared__ ushort_t xw[64*RSX];
    __shared__ ushort_t Bt[128*RSB];
    __shared__ float Acs[CHUNK];
    __shared__ float dts[CHUNK];
    int bid = blockIdx.x;
    int h = bid % NHEADS;
    int c = (bid / NHEADS) % NC;
    int b = bid / (NHEADS*NC);
    int tid = threadIdx.x;
    int lane = tid & 63, wave = tid >> 6;
    int lm = lane & 15, quad = lane >> 4;
    Acs[tid] = Acum[((size_t)(b*NHEADS + h))*SEQL + c*CHUNK + tid];
    dts[tid] = dtH[((size_t)(b*NHEADS + h))*SEQL + c*CHUNK + tid];
    __syncthreads();
    float AcL = Acs[CHUNK-1];
    {
        const ushort_t* xg = convb + ((size_t)(b*SEQL + c*CHUNK))*CONVD + h*HD;
        #pragma unroll
        for (int j8 = 0; j8 < 8; j8++){
            int s0 = wave*64 + j8*8;
            bf16x8 pk;
            #pragma unroll
            for (int j = 0; j < 8; j++){
                int l = s0 + j;
                pk[j] = (short)f2b(expf(AcL - Acs[l]) * dts[l] * b2f(xg[(size_t)l*CONVD + lane]));
            }
            *(bf16x8*)&xw[lane*RSX + s0] = pk;
        }
    }
    f32x4 acc[8];
    #pragma unroll
    for (int j=0;j<8;j++) acc[j] = (f32x4){0.f,0.f,0.f,0.f};
    const ushort_t* bbase = convb + ((size_t)(b*SEQL + c*CHUNK))*CONVD + DI;
    int tn = tid & 127, lg = tid >> 7;             // conflict-free Bt staging
    for (int l0 = 0; l0 < CHUNK; l0 += 64){
        __syncthreads();
        #pragma unroll
        for (int p = 0; p < 4; p++){
            int lbase = lg*32 + p*8;
            bf16x8 pk;
            #pragma unroll
            for (int j = 0; j < 8; j++)
                pk[j] = (short)bbase[(size_t)(l0 + lbase + j)*CONVD + tn];
            *(bf16x8*)&Bt[tn*RSB + lbase] = pk;
        }
        __syncthreads();
        #pragma unroll
        for (int kk = 0; kk < 2; kk++){
            bf16x8 af = *(const bf16x8*)&xw[(wave*16+lm)*RSX + l0 + kk*32 + quad*8];
            #pragma unroll
            for (int nt = 0; nt < 8; nt++){
                bf16x8 bfr = *(const bf16x8*)&Bt[(nt*16+lm)*RSB + kk*32 + quad*8];
                acc[nt] = __builtin_amdgcn_mfma_f32_16x16x32_bf16(af, bfr, acc[nt], 0, 0, 0);
            }
        }
    }
    float* outp = states + ((size_t)((b*NC + c)*NHEADS + h))*(HD*DSTATE);
    #pragma unroll
    for (int nt = 0; nt < 8; nt++)
        #pragma unroll
        for (int r = 0; r < 4; r++)
            outp[(size_t)(wave*16 + quad*4 + r)*DSTATE + nt*16 + lm] = acc[nt][r];
}

// ------------- inter-chunk recurrence, 16-way split over (p,n) elements
__global__ __launch_bounds__(256) void prev_scan_k(const float* __restrict__ states,
                                                   const float* __restrict__ Acum,
                                                   float* __restrict__ prev){
    int bid = blockIdx.x;                  // B*NHEADS*16
    int part = bid & 15;
    int h = (bid >> 4) & (NHEADS-1);
    int b = bid >> 9;
    int tid = threadIdx.x;
    const float* AcB = Acum + ((size_t)(b*NHEADS + h))*SEQL;
    float dec[NC];
    #pragma unroll
    for (int c = 0; c < NC; c++) dec[c] = expf(AcB[c*CHUNK + CHUNK-1]);
    #pragma unroll
    for (int j = 0; j < 2; j++){
        int e = part*512 + j*256 + tid;
        float carry = 0.f;
        #pragma unroll
        for (int c = 0; c < NC; c++){
            size_t idx = ((size_t)((b*NC + c)*NHEADS + h))*(HD*DSTATE) + e;
            prev[idx] = carry;
            carry = carry*dec[c] + states[idx];
        }
    }
}

// ===== MFMA SSD output: Y = P@(dt*xs) + (e^A C)@prev^T + D*xs  -> bf16 Ybf
#define RLX 264
#define RLP 136
__global__ __launch_bounds__(256) void y_mfma_k(const ushort_t* __restrict__ convb,
                                                const ushort_t* __restrict__ G,
                                                const float* __restrict__ Acum,
                                                const float* __restrict__ dtH,
                                                const float* __restrict__ prev,
                                                const float* __restrict__ Dp,
                                                ushort_t* __restrict__ Ybf){
    __shared__ ushort_t xdtT[64*RLX];
    __shared__ ushort_t prevs[64*RLP];
    __shared__ float Acs[CHUNK];
    __shared__ float dts[CHUNK];
    int bid = blockIdx.x;
    int h = bid % NHEADS;
    int c = (bid / NHEADS) % NC;
    int b = bid / (NHEADS*NC);
    int tid = threadIdx.x;
    int lane = tid & 63, wave = tid >> 6;
    int lm = lane & 15, quad = lane >> 4;

    Acs[tid] = Acum[((size_t)(b*NHEADS + h))*SEQL + c*CHUNK + tid];
    dts[tid] = dtH[((size_t)(b*NHEADS + h))*SEQL + c*CHUNK + tid];
    {
        const float* pv = prev + ((size_t)((b*NC + c)*NHEADS + h))*(HD*DSTATE);
        #pragma unroll
        for (int i = 0; i < 32; i++){
            int e = tid + i*256; int p = e >> 7, n = e & 127;
            prevs[p*RLP + n] = f2b(pv[e]);
        }
    }
    __syncthreads();
    {
        const ushort_t* xg = convb + ((size_t)(b*SEQL + c*CHUNK))*CONVD + h*HD;
        #pragma unroll
        for (int j8 = 0; j8 < 8; j8++){
            int s0 = wave*64 + j8*8;
            bf16x8 pk;
            #pragma unroll
            for (int j = 0; j < 8; j++){
                int l = s0 + j;
                pk[j] = (short)f2b(b2f(xg[(size_t)l*CONVD + lane]) * dts[l]);
            }
            *(bf16x8*)&xdtT[lane*RLX + s0] = pk;
        }
    }
    __syncthreads();

    int   lrow[4];  float Alr[4], eAlr[4];
    #pragma unroll
    for (int mt = 0; mt < 4; mt++){
        lrow[mt] = (mt*4 + wave)*16 + lm;
        Alr[mt]  = Acs[lrow[mt]];
        eAlr[mt] = expf(Alr[mt]);
    }
    const ushort_t* Gbase = G + ((size_t)(b*NC + c))*(CHUNK*CHUNK);

    f32x4 acc[4][4];
    #pragma unroll
    for (int i=0;i<4;i++)
        #pragma unroll
        for (int j=0;j<4;j++) acc[i][j] = (f32x4){0.f,0.f,0.f,0.f};

    for (int ks = 0; ks < 8; ks++){
        bf16x8 bfr[4];
        #pragma unroll
        for (int nt = 0; nt < 4; nt++)
            bfr[nt] = *(const bf16x8*)&xdtT[(nt*16+lm)*RLX + ks*32 + quad*8];
        #pragma unroll
        for (int mt = 0; mt < 4; mt++){
            int rblk = mt*4 + wave;
            int nst = rblk/2 + 1;
            if (ks < nst){
                int sbase = ks*32 + quad*8;
                bf16x8 g8 = *(const bf16x8*)&Gbase[(size_t)lrow[mt]*CHUNK + sbase];
                const float4* A4 = (const float4*)(&Acs[sbase]);
                float4 a0 = A4[0], a1 = A4[1];
                float Al = Alr[mt]; int l = lrow[mt];
                float pv[8];
                pv[0] = (sbase+0 <= l) ? b2f((ushort_t)g8[0])*expf(Al - a0.x) : 0.f;
                pv[1] = (sbase+1 <= l) ? b2f((ushort_t)g8[1])*expf(Al - a0.y) : 0.f;
                pv[2] = (sbase+2 <= l) ? b2f((ushort_t)g8[2])*expf(Al - a0.z) : 0.f;
                pv[3] = (sbase+3 <= l) ? b2f((ushort_t)g8[3])*expf(Al - a0.w) : 0.f;
                pv[4] = (sbase+4 <= l) ? b2f((ushort_t)g8[4])*expf(Al - a1.x) : 0.f;
                pv[5] = (sbase+5 <= l) ? b2f((ushort_t)g8[5])*expf(Al - a1.y) : 0.f;
                pv[6] = (sbase+6 <= l) ? b2f((ushort_t)g8[6])*expf(Al - a1.z) : 0.f;
                pv[7] = (sbase+7 <= l) ? b2f((ushort_t)g8[7])*expf(Al - a1.w) : 0.f;
                bf16x8 af;
                #pragma unroll
                for (int j = 0; j < 8; j++) af[j] = (short)f2b(pv[j]);
                #pragma unroll
                for (int nt = 0; nt < 4; nt++)
                    acc[mt][nt] = __builtin_amdgcn_mfma_f32_16x16x32_bf16(af, bfr[nt], acc[mt][nt], 0, 0, 0);
            }
        }
    }
    for (int kc = 0; kc < 4; kc++){
        bf16x8 bfr[4];
        #pragma unroll
        for (int nt = 0; nt < 4; nt++)
            bfr[nt] = *(const bf16x8*)&prevs[(nt*16+lm)*RLP + kc*32 + quad*8];
        #pragma unroll
        for (int mt = 0; mt < 4; mt++){
            int rowg = b*SEQL + c*CHUNK + lrow[mt];
            bf16x8 c8 = *(const bf16x8*)&convb[(size_t)rowg*CONVD + DI + DSTATE + kc*32 + quad*8];
            float e = eAlr[mt];
            bf16x8 af;
            #pragma unroll
            for (int j = 0; j < 8; j++) af[j] = (short)f2b(e * b2f((ushort_t)c8[j]));
            #pragma unroll
            for (int nt = 0; nt < 4; nt++)
                acc[mt][nt] = __builtin_amdgcn_mfma_f32_16x16x32_bf16(af, bfr[nt], acc[mt][nt], 0, 0, 0);
        }
    }
    float Dv = Dp[h];
    #pragma unroll
    for (int mt = 0; mt < 4; mt++){
        int l0 = (mt*4 + wave)*16 + quad*4;
        #pragma unroll
        for (int nt = 0; nt < 4; nt++){
            int p = nt*16 + lm;
            #pragma unroll
            for (int r = 0; r < 4; r++){
                int rowg = b*SEQL + c*CHUNK + l0 + r;
                float xs = b2f(convb[(size_t)rowg*CONVD + h*HD + p]);
                Ybf[(size_t)rowg*DI + h*HD + p] = f2b(acc[mt][nt][r] + Dv*xs);
            }
        }
    }
}

// ---------- y = Y*silu(z); RMSNorm; * rms_w ; -> bf16 (8 elems/thread, b128)
__global__ __launch_bounds__(256) void gate_rms_k(const ushort_t* __restrict__ Yb,
                                                  const ushort_t* __restrict__ zx,
                                                  const float* __restrict__ rms_w,
                                                  ushort_t* __restrict__ yn){
    __shared__ float red[4];
    __shared__ float scale_s;
    int row = blockIdx.x; int tid = threadIdx.x;
    int d0 = tid*8;
    bf16x8 y8 = *(const bf16x8*)&Yb[(size_t)row*DI + d0];
    bf16x8 z8 = *(const bf16x8*)&zx[(size_t)row*DPROJ + d0];
    float v[8]; float ss = 0.f;
    #pragma unroll
    for (int j = 0; j < 8; j++){
        float g = b2f((ushort_t)y8[j]) * silu_f(b2f((ushort_t)z8[j]));
        v[j] = g; ss += g*g;
    }
    #pragma unroll
    for (int off = 32; off > 0; off >>= 1) ss += __shfl_down(ss, off);
    int lane = tid & 63, wid = tid >> 6;
    if (lane == 0) red[wid] = ss;
    __syncthreads();
    if (tid == 0) scale_s = rsqrtf((red[0]+red[1]+red[2]+red[3])*(1.f/DI) + 1e-12f);
    __syncthreads();
    float sc = scale_s;
    float4 w0 = *(const float4*)&rms_w[d0];
    float4 w1 = *(const float4*)&rms_w[d0+4];
    float wv[8] = {w0.x,w0.y,w0.z,w0.w,w1.x,w1.y,w1.z,w1.w};
    bf16x8 o;
    #pragma unroll
    for (int j = 0; j < 8; j++) o[j] = (short)f2b(v[j]*sc*wv[j]);
    *(bf16x8*)&yn[(size_t)row*DI + d0] = o;
}

// -------- LN(a + a2 + resid_f32) -> bf16 only (mid LN), float4 loads
__global__ __launch_bounds__(256) void ln_hbf_k(const float* __restrict__ a,
                                                const float* __restrict__ a2,
                                                const float* __restrict__ resid,
                                                const float* __restrict__ g,
                                                const float* __restrict__ bw,
                                                ushort_t* __restrict__ bfout){
    __shared__ float redA[4], redB[4];
    __shared__ float mu_s, rs_s;
    int row = blockIdx.x; int tid = threadIdx.x;
    int d0 = tid*4;
    float4 va = *(const float4*)&a[(size_t)row*DM + d0];
    float4 vb = *(const float4*)&a2[(size_t)row*DM + d0];
    float4 vr = *(const float4*)&resid[(size_t)row*DM + d0];
    float u[4] = {va.x+vb.x+vr.x, va.y+vb.y+vr.y, va.z+vb.z+vr.z, va.w+vb.w+vr.w};
    float s = u[0]+u[1]+u[2]+u[3];
    float s2 = u[0]*u[0]+u[1]*u[1]+u[2]*u[2]+u[3]*u[3];
    #pragma unroll
    for (int off = 32; off > 0; off >>= 1){
        s  += __shfl_down(s,  off);
        s2 += __shfl_down(s2, off);
    }
    int lane = tid & 63, wid = tid >> 6;
    if (lane == 0){ redA[wid] = s; redB[wid] = s2; }
    __syncthreads();
    if (tid == 0){
        float S  = redA[0]+redA[1]+redA[2]+redA[3];
        float S2 = redB[0]+redB[1]+redB[2]+redB[3];
        float mu = S*(1.f/DM);
        float var = S2*(1.f/DM) - mu*mu;
        mu_s = mu; rs_s = rsqrtf(var + 1e-12f);
    }
    __syncthreads();
    float mu = mu_s, rs = rs_s;
    float4 gg = *(const float4*)&g[d0];
    float4 bb = *(const float4*)&bw[d0];
    float gv[4] = {gg.x,gg.y,gg.z,gg.w}, bv[4] = {bb.x,bb.y,bb.z,bb.w};
    short4 o;
    o.x = (short)f2b((u[0]-mu)*rs*gv[0] + bv[0]);
    o.y = (short)f2b((u[1]-mu)*rs*gv[1] + bv[1]);
    o.z = (short)f2b((u[2]-mu)*rs*gv[2] + bv[2]);
    o.w = (short)f2b((u[3]-mu)*rs*gv[3] + bv[3]);
    *(short4*)&bfout[(size_t)row*DM + d0] = o;
}

// -------- final LN(a + a2 + resid_bf16) -> fp32 d_out; extra blocks copy td
__global__ __launch_bounds__(256) void ln_final_k(const float* __restrict__ a,
                                                  const float* __restrict__ a2,
                                                  const ushort_t* __restrict__ residb,
                                                  const float* __restrict__ g,
                                                  const float* __restrict__ bw,
                                                  float* __restrict__ outp,
                                                  const float* __restrict__ td){
    __shared__ float redA[4], redB[4];
    __shared__ float mu_s, rs_s;
    int row = blockIdx.x; int tid = threadIdx.x;
    if (row >= ROWS){
        int idx = (row - ROWS)*256 + tid;
        outp[(size_t)ROWS*DM + idx] = td[idx];
        return;
    }
    int d0 = tid*4;
    float4 va = *(const float4*)&a[(size_t)row*DM + d0];
    float4 vb = *(const float4*)&a2[(size_t)row*DM + d0];
    short4 r4 = *(const short4*)&residb[(size_t)row*DM + d0];
    float u[4] = {va.x+vb.x+b2f((ushort_t)r4.x), va.y+vb.y+b2f((ushort_t)r4.y),
                  va.z+vb.z+b2f((ushort_t)r4.z), va.w+vb.w+b2f((ushort_t)r4.w)};
    float s = u[0]+u[1]+u[2]+u[3];
    float s2 = u[0]*u[0]+u[1]*u[1]+u[2]*u[2]+u[3]*u[3];
    #pragma unroll
    for (int off = 32; off > 0; off >>= 1){
        s  += __shfl_down(s,  off);
        s2 += __shfl_down(s2, off);
    }
    int lane = tid & 63, wid = tid >> 6;
    if (lane == 0){ redA[wid] = s; redB[wid] = s2; }
    __syncthreads();
    if (tid == 0){
        float S  = redA[0]+redA[1]+redA[2]+redA[3];
        float S2 = redB[0]+redB[1]+redB[2]+redB[3];
        float mu = S*(1.f/DM);
        float var = S2*(1.f/DM) - mu*mu;
        mu_s = mu; rs_s = rsqrtf(var + 1e-12f);
    }
    __syncthreads();
    float mu = mu_s, rs = rs_s;
    float4 gg = *(const float4*)&g[d0];
    float4 bb = *(const float4*)&bw[d0];
    float4 o;
    o.x = (u[0]-mu)*rs*gg.x + bb.x;
    o.y = (u[1]-mu)*rs*gg.y + bb.y;
    o.z = (u[2]-mu)*rs*gg.z + bb.z;
    o.w = (u[3]-mu)*rs*gg.w + bb.w;
    *(float4*)&outp[(size_t)row*DM + d0] = o;
}

extern "C" void kernel_launch(void* const* d_in, const int* in_sizes, int n_in,
                              void* d_out, int out_size, void* d_ws, size_t ws_size,
                              hipStream_t stream){
    const float* x         = (const float*)d_in[0];
    const float* time_diff = (const float*)d_in[1];
    const float* W_in      = (const float*)d_in[2];
    const float* b_in      = (const float*)d_in[3];
    const float* conv_w    = (const float*)d_in[4];
    const float* conv_b    = (const float*)d_in[5];
    const float* A_log     = (const float*)d_in[6];
    const float* dt_bias   = (const float*)d_in[7];
    const float* Dp        = (const float*)d_in[8];
    const float* time_dec  = (const float*)d_in[9];
    const float* rms_w     = (const float*)d_in[10];
    const float* W_out     = (const float*)d_in[11];
    const float* b_out     = (const float*)d_in[12];
    const float* ln_g      = (const float*)d_in[13];
    const float* ln_b      = (const float*)d_in[14];
    const float* fc1_w     = (const float*)d_in[15];
    const float* fc1_b     = (const float*)d_in[16];
    const float* fc2_w     = (const float*)d_in[17];
    const float* fc2_b     = (const float*)d_in[18];
    const float* ln2_g     = (const float*)d_in[19];
    const float* ln2_b     = (const float*)d_in[20];

    float* ws = (float*)d_ws;
    float* zx    = ws;                       // region1: 17,956,864 f
    float* convb = zx    + 17956864;         // region2:  9,437,184 f
    float* dtH   = convb + 9437184;
    float* Acum  = dtH   + 131072;
    float* r4    = Acum  + 131072;           // region4:  8,388,608 f
    float* r5    = r4    + 8388608;          // region5:  9,437,184 f
    float* ybreg = r5    + 9437184;          // region6:  4,194,304 f
    // region1 aliases
    ushort_t* zx_bf  = (ushort_t*)zx;                 // steps 2-8
    float*    dtaux  = zx + 10600000;                 // steps 2-3
    ushort_t* mid_bf = (ushort_t*)zx;                 // steps 12-13 (zx dead)
    ushort_t* h_bf   = (ushort_t*)(zx + 8388608);     // steps 11-14 (zx dead)
    // region2 aliases
    ushort_t* convb_bf = (ushort_t*)convb;            // steps 3-7
    float* outPa  = convb;                            // steps 10-11 (convb dead)
    // region4 aliases
    ushort_t* x_bf  = (ushort_t*)r4;                  // steps 1-2
    ushort_t* WinT  = (ushort_t*)(r4 + 2097152);      // steps 1-2
    ushort_t* WoutT = (ushort_t*)(r4 + 4194304);      // steps 9-10
    float* fc2Pa = r4;                                // steps 13-14
    // region5 aliases
    ushort_t* Gb   = (ushort_t*)r5;                   // steps 4-7
    float* stat = r5 + 1048576;                       // steps 5-6
    float* prev = stat + 4194304;                     // steps 6-7
    ushort_t* yn_bf = (ushort_t*)r5;                  // steps 8-10 (G/stat dead)
    ushort_t* fc1T  = (ushort_t*)(r5 + 4194304);      // steps 9-12 (stat/prev dead)
    ushort_t* fc2T  = (ushort_t*)(r5 + 6291456);      // steps 9-13 (prev dead)
    // region6
    ushort_t* Ybf = (ushort_t*)ybreg;                 // steps 7-8
    float* outp   = (float*)d_out;

    // 1. f2b(x) + W_in^T (merged, vectorized)
    prep_in_k<<<2048 + 4480, 256, 0, stream>>>(x, x_bf, W_in, WinT);
    // 2. in-proj (M=4096,N=4384,K=1024) -> bf16 zx + fp32 dt sidecar
    mfma_gemm_k<0,1,128,1,1><<<dim3(35, ROWS/128), 256, 0, stream>>>(x_bf, WinT, b_in, nullptr, zx_bf, dtaux, ROWS, DPROJ, DM, DPROJ);
    // 3. conv+SiLU (vectorized) -> bf16 convb, merged with dt/dA/cumsum scan
    conv_dt_k<<<CONVBLKS + BATCH*NHEADS*NC, 256, 0, stream>>>(zx_bf, conv_w, conv_b, convb_bf,
                                                              dtaux, time_diff, A_log, dt_bias, time_dec, dtH, Acum);
    // 4. G = C @ B^T (MFMA, bf16)
    g_mfma_k<<<dim3(4,4,BATCH*NC), 256, 0, stream>>>(convb_bf, Gb);
    // 5. per-chunk states (MFMA, conflict-free Bt staging)
    states_mfma_k<<<BATCH*NC*NHEADS, 256, 0, stream>>>(convb_bf, dtH, Acum, stat);
    // 6. inter-chunk scan (1024 blocks)
    prev_scan_k<<<BATCH*NHEADS*16, 256, 0, stream>>>(stat, Acum, prev);
    // 7. MFMA SSD output -> bf16 Y
    y_mfma_k<<<BATCH*NC*NHEADS, 256, 0, stream>>>(convb_bf, Gb, Acum, dtH, prev, Dp, Ybf);
    // 8. gate + RMSNorm -> bf16 yn (vectorized)
    gate_rms_k<<<ROWS, 256, 0, stream>>>(Ybf, zx_bf, rms_w, yn_bf);
    // 9. W_out / fc1 / fc2 transposes (merged)
    transpose3_k<<<10240, 256, 0, stream>>>(W_out, fc1_w, fc2_w, WoutT, fc1T, fc2T);
    // 10. out-proj split-K=2 (M=4096,N=1024,K=2048)
    mfma_gemm_k<0,0,64,2,0><<<dim3(DM/64, ROWS/128, 2), 256, 0, stream>>>(yn_bf, WoutT, b_out, outPa, nullptr, nullptr, ROWS, DM, DI, DM);
    // 11. h = LN(Pa + Pb + x) -> bf16 only (vectorized)
    ln_hbf_k<<<ROWS, 256, 0, stream>>>(outPa, outPa + (size_t)ROWS*DM, x, ln_g, ln_b, h_bf);
    // 12. fc1 + hardswish -> bf16 mid (M=4096,N=4096,K=1024)
    mfma_gemm_k<1,1,128,1,0><<<dim3(DFF/128, ROWS/128), 256, 0, stream>>>(h_bf, fc1T, fc1_b, nullptr, mid_bf, nullptr, ROWS, DFF, DM, DFF);
    // 13. fc2 split-K=2 (M=4096,N=1024,K=4096)
    mfma_gemm_k<0,0,64,2,0><<<dim3(DM/64, ROWS/128, 2), 256, 0, stream>>>(mid_bf, fc2T, fc2_b, fc2Pa, nullptr, nullptr, ROWS, DM, DFF, DM);
    // 14. out = LN(Pa + Pb + h_bf) + td passthrough (merged, vectorized)
    ln_final_k<<<ROWS + ROWS/256, 256, 0, stream>>>(fc2Pa, fc2Pa + (size_t)ROWS*DM, h_bf, ln2_g, ln2_b, outp, time_diff);
}